// Round 4
// baseline (617.872 us; speedup 1.0000x reference)
//
#include <hip/hip_runtime.h>
#include <hip/hip_bf16.h>
#include <cstdint>
#include <cstddef>

// ResNet CG-gated basic block, MI355X gfx950.
// conv_cg: block = 4 rows x 56 cols (224 px) x 256 outs, 512 threads (8 waves,
// wave = 112px x 64o). A patch (6x58x64ch, 44.5KB) dbuf, staged once per cb,
// reused by 9 taps. B (32KB per tap-cb) dbuf. All staging via global_load_lds
// with counted vmcnt (never drained in-loop). yp held packed bf16 in regs.
// Grid 224 = 1 block/CU, single round. LDS 152KB static.

typedef __attribute__((ext_vector_type(8))) short bf16x8;
typedef __attribute__((ext_vector_type(4))) float f32x4;
typedef __attribute__((ext_vector_type(8))) unsigned short u16x8;

#define HP 58
#define WP 58
#define CIN 256
#define NIMG 16

#define A_BUF 45056
#define B0_OFF 90112
#define B1_OFF 122880

__device__ __forceinline__ unsigned short f2bf(float f) {
  unsigned int u = __float_as_uint(f);
  u += 0x7fffu + ((u >> 16) & 1u);   // RNE
  return (unsigned short)(u >> 16);
}

#define GLOAD16(gp, lp)                                                        \
  __builtin_amdgcn_global_load_lds(                                            \
      (const __attribute__((address_space(1))) void*)(gp),                     \
      (__attribute__((address_space(3))) void*)(lp), 16, 0, 0)
#define GLOAD4(gp, lp)                                                         \
  __builtin_amdgcn_global_load_lds(                                            \
      (const __attribute__((address_space(1))) void*)(gp),                     \
      (__attribute__((address_space(3))) void*)(lp), 4, 0, 0)

// ---------------------------------------------------------------- hpad borders
__global__ void zero_borders(unsigned short* __restrict__ pad) {
  int b = blockIdx.x;              // 16*58
  int img = b / 58, yp = b - img * 58;
  int tid = threadIdx.x;
  u16x8 z = {0, 0, 0, 0, 0, 0, 0, 0};
  unsigned short* row = pad + ((size_t)(img * HP + yp)) * WP * CIN;
  if (yp == 0 || yp == HP - 1) {
    for (int i = tid; i < WP * CIN / 8; i += 256) ((u16x8*)row)[i] = z;
  } else {
    if (tid < 32) ((u16x8*)row)[tid] = z;                                // x=0
    else if (tid < 64) ((u16x8*)row)[(WP - 1) * CIN / 8 + tid - 32] = z; // x=57
  }
}

// ---------------------------------------------------------------- weights
// w OIHW f32 -> Bt[tap][cb][256 o][64 c] bf16 (32KB per (tap,cb) chunk)
__global__ void prep_w(const float* __restrict__ wa, const float* __restrict__ wb,
                       unsigned short* __restrict__ bta, unsigned short* __restrict__ btb) {
  int id = blockIdx.x * 256 + threadIdx.x;   // 0 .. 131071
  const float* w = (id < 65536) ? wa : wb;
  unsigned short* bt = (id < 65536) ? bta : btb;
  int oi = id & 65535;
  int o = oi >> 8, i = oi & 255;
  int cb = i >> 6, c = i & 63;
  float v[9];
#pragma unroll
  for (int t = 0; t < 9; ++t) v[t] = w[(size_t)oi * 9 + t];
#pragma unroll
  for (int t = 0; t < 9; ++t)
    bt[((size_t)((t * 4 + cb) * 256 + o)) * 64 + c] = f2bf(v[t]);
}

// ------------------------------------------ x: NCHW f32 -> padded NHWC bf16 (+borders)
__global__ void prep_x(const float* __restrict__ x, unsigned short* __restrict__ xpad) {
  __shared__ float ld[56 * 65];
  int b = blockIdx.x;              // 16*58 padded rows
  int img = b / 58, y = b - img * 58;
  int tid = threadIdx.x;
  unsigned short* row = xpad + ((size_t)(img * HP + y)) * WP * CIN;
  u16x8 z = {0, 0, 0, 0, 0, 0, 0, 0};
  if (y == 0 || y == HP - 1) {
#pragma unroll
    for (int it = 0; it < 8; ++it) {
      int i = it * 256 + tid;
      if (i < WP * CIN / 8) ((u16x8*)row)[i] = z;
    }
    return;
  }
  if (tid < 32) ((u16x8*)row)[tid] = z;
  else if (tid < 64) ((u16x8*)row)[(WP - 1) * CIN / 8 + tid - 32] = z;
  int ys = y - 1;
  for (int cb = 0; cb < 4; ++cb) {
    __syncthreads();
#pragma unroll
    for (int it = 0; it < 14; ++it) {
      int i = tid + it * 256;                      // 64 ch * 56 x
      int cl = i / 56, xx = i - cl * 56;
      ld[xx * 65 + cl] = x[((size_t)(img * 256 + cb * 64 + cl) * 56 + ys) * 56 + xx];
    }
    __syncthreads();
#pragma unroll
    for (int it = 0; it < 14; ++it) {
      int j = tid + it * 256;
      int xx = j >> 6, c = j & 63;
      row[(xx + 1) * CIN + cb * 64 + c] = f2bf(ld[xx * 65 + c]);
    }
  }
}

// ---------------------------------------------------------------- CG conv + BN
template <int LAYER>
__global__ __launch_bounds__(512, 2)
void conv_cg(const unsigned short* __restrict__ inp,   // [16][58][58][256] bf16
             const unsigned short* __restrict__ Bt,    // [9][4][256][64] bf16
             const float* __restrict__ theta,
             const float* __restrict__ gammav,
             const float* __restrict__ betav,
             const float* __restrict__ meanv,
             const float* __restrict__ varv,
             unsigned short* __restrict__ hout,        // LAYER==1
             const float* __restrict__ xres,           // LAYER==2
             float* __restrict__ dout)                 // LAYER==2
{
  __shared__ alignas(16) char smem[155648];  // A0|A1 (45056 ea) B0|B1 (32768 ea)

  const int tid = threadIdx.x;
  const int lane = tid & 63;
  const int wid = tid >> 6;
  const int wm = wid >> 2, wn = wid & 3;     // wave = px-half x o-quarter
  const int l15 = lane & 15, l4 = lane >> 4;

  int bx = blockIdx.x;
  int sw = (bx & 7) * 28 + (bx >> 3);        // XCD-bijective (224 = 8*28)
  const int img = sw / 14, rg = sw - img * 14;   // row-group: rows rg*4..rg*4+3
  const size_t img_base = (size_t)img * (HP * WP * CIN);
  const char* inb = (const char*)(inp + img_base);
  const char* Btb = (const char*)Bt;

  // ---- staging source offsets (bytes), per-thread
  int a16off[5];
#pragma unroll
  for (int it = 0; it < 5; ++it) {
    int u = it * 512 + tid;                  // 16B unit, px p = u>>3 (<=319)
    int p = u >> 3, s = u & 7;
    int pr = p / 58, pc = p - pr * 58;
    a16off[it] = (((rg * 4 + pr) * 58) + pc) * 512 + ((s ^ (p & 7)) << 4);
  }
  int a4off[2];
#pragma unroll
  for (int it = 0; it < 2; ++it) {
    int j = it * 512 + tid;
    int jc = j > 895 ? 895 : j;              // clamp (pad region never read)
    int bb = 40960 + jc * 4;
    int p = bb >> 7;
    int pr = p / 58, pc = p - pr * 58;
    a4off[it] = (((rg * 4 + pr) * 58) + pc) * 512 +
                ((((bb >> 4) & 7) ^ (p & 7)) << 4) + (bb & 15);
  }
  int boff[4];
#pragma unroll
  for (int it = 0; it < 4; ++it) {
    int u = it * 512 + tid;
    int o = u >> 3, s = u & 7;
    boff[it] = o * 128 + ((s ^ (o & 7)) << 4);
  }
  // ---- MFMA read precomputes
  int pb[7];
#pragma unroll
  for (int mi = 0; mi < 7; ++mi) {
    int pl = mi * 16 + l15;                  // wave-local px 0..111
    int ar = pl / 56, ac = pl - ar * 56;
    pb[mi] = (wm * 2 + ar + 1) * 58 + ac + 1;
  }
  int ro128[4], rx7[4];
#pragma unroll
  for (int ni = 0; ni < 4; ++ni) {
    int ro = wn * 64 + ni * 16 + l15;
    ro128[ni] = ro << 7;
    rx7[ni] = ro & 7;
  }

  auto stageA = [&](int abuf, int cb) {
    const char* s0 = inb + cb * 128;
#pragma unroll
    for (int it = 0; it < 5; ++it)
      GLOAD16(s0 + a16off[it], smem + abuf + it * 8192 + wid * 1024);
#pragma unroll
    for (int it = 0; it < 2; ++it)
      GLOAD4(s0 + a4off[it], smem + abuf + 40960 + it * 2048 + wid * 256);
  };
  auto stageB = [&](int bbuf, int chunk) {   // chunk = tap*4+cb
    const char* s0 = Btb + (size_t)chunk * 32768;
#pragma unroll
    for (int it = 0; it < 4; ++it)
      GLOAD16(s0 + boff[it], smem + bbuf + it * 8192 + wid * 1024);
  };

  f32x4 acc[7][4];
  unsigned int ypk[7][4][2];
  const f32x4 fzero = {0.f, 0.f, 0.f, 0.f};
#pragma unroll
  for (int i = 0; i < 7; ++i)
#pragma unroll
    for (int j = 0; j < 4; ++j) acc[i][j] = fzero;

  stageA(0, 0);
  stageB(B0_OFF, 0);

  for (int cb = 0; cb < 4; ++cb) {
    const char* Abp = smem + ((cb & 1) ? A_BUF : 0);
    const int An = (cb & 1) ? 0 : A_BUF;
#pragma unroll
    for (int tap = 0; tap < 9; ++tap) {
      const int dy = tap / 3 - 1, dxx = tap % 3 - 1;
      const char* Bcp = smem + (((cb + tap) & 1) ? B1_OFF : B0_OFF);
      const int Bn = ((cb + tap) & 1) ? B0_OFF : B1_OFF;
      // issue next-chunk stages (stay in flight across the barrier)
      if (tap < 8)       stageB(Bn, (tap + 1) * 4 + cb);
      else if (cb < 3)   stageB(Bn, 0 * 4 + (cb + 1));
      if (tap == 0 && cb < 3) stageA(An, cb + 1);
      // counted wait: drain current B (and A at cb start) only
      if (cb == 3 && tap == 8)
        asm volatile("s_waitcnt vmcnt(0)" ::: "memory");
      else if (tap <= 1 && cb < 3)
        asm volatile("s_waitcnt vmcnt(11)" ::: "memory");
      else
        asm volatile("s_waitcnt vmcnt(4)" ::: "memory");
      __builtin_amdgcn_s_barrier();
      __builtin_amdgcn_s_setprio(1);
#pragma unroll
      for (int ks = 0; ks < 2; ++ks) {
        bf16x8 av[7], bv[4];
#pragma unroll
        for (int mi = 0; mi < 7; ++mi) {
          int p = pb[mi] + dy * 58 + dxx;
          av[mi] = *(const bf16x8*)(Abp + p * 128 +
                                    (((ks * 4 + l4) ^ (p & 7)) << 4));
        }
#pragma unroll
        for (int ni = 0; ni < 4; ++ni)
          bv[ni] = *(const bf16x8*)(Bcp + ro128[ni] +
                                    (((ks * 4 + l4) ^ rx7[ni]) << 4));
#pragma unroll
        for (int mi = 0; mi < 7; ++mi)
#pragma unroll
          for (int ni = 0; ni < 4; ++ni)
            acc[mi][ni] = __builtin_amdgcn_mfma_f32_16x16x32_bf16(
                av[mi], bv[ni], acc[mi][ni], 0, 0, 0);
      }
      __builtin_amdgcn_s_setprio(0);
      __builtin_amdgcn_s_barrier();
    }
    if (cb == 0) {   // yp complete -> pack to bf16 pairs, reset acc
#pragma unroll
      for (int mi = 0; mi < 7; ++mi)
#pragma unroll
        for (int ni = 0; ni < 4; ++ni) {
          ypk[mi][ni][0] = (unsigned int)f2bf(acc[mi][ni][0]) |
                           ((unsigned int)f2bf(acc[mi][ni][1]) << 16);
          ypk[mi][ni][1] = (unsigned int)f2bf(acc[mi][ni][2]) |
                           ((unsigned int)f2bf(acc[mi][ni][3]) << 16);
          acc[mi][ni] = fzero;
        }
    }
  }

  // ---- epilogue: gate + BN (+relu / +residual); LDS all free, per-wave slice
  char* slice = smem + wid * 19456;
  float th[4], sc[4], bi[4];
#pragma unroll
  for (int ni = 0; ni < 4; ++ni) {
    int o = wn * 64 + ni * 16 + l15;
    th[ni] = theta[o];
    float inv = gammav[o] * rsqrtf(varv[o] + 1e-5f);
    sc[ni] = inv;
    bi[ni] = betav[o] - meanv[o] * inv;
  }

  if (LAYER == 1) {
    // stage wave tile [112 px][64 o] bf16 (row stride 144B), store NHWC
#pragma unroll
    for (int mi = 0; mi < 7; ++mi)
#pragma unroll
      for (int ni = 0; ni < 4; ++ni)
#pragma unroll
        for (int q = 0; q < 4; ++q) {
          int pl = mi * 16 + l4 * 4 + q;
          unsigned int pk = ypk[mi][ni][q >> 1];
          float yp = __uint_as_float((q & 1) ? (pk & 0xffff0000u) : (pk << 16));
          float yr = acc[mi][ni][q];
          float dg = 1.f / (1.f + __expf(-2.f * (yp - th[ni])));
          float v = fmaxf((yp + dg * yr) * sc[ni] + bi[ni], 0.f);
          *(unsigned short*)(slice + pl * 144 + (ni * 16 + l15) * 2) = f2bf(v);
        }
#pragma unroll
    for (int it = 0; it < 14; ++it) {
      int j = it * 64 + lane;                // 112 px * 8 octets
      int pl = j >> 3, s = j & 7;
      int lr = pl / 56, xc = pl - lr * 56;
      int gy = rg * 4 + wm * 2 + lr + 1, gx = xc + 1;
      u16x8 tv = *(const u16x8*)(slice + pl * 144 + s * 16);
      *(u16x8*)(hout + img_base + ((size_t)(gy * WP + gx)) * CIN +
                wn * 64 + s * 8) = tv;
    }
  } else {
    // two o-halves of 32: stage [32 o][112 px] f32 (row stride 464B)
#pragma unroll
    for (int r2 = 0; r2 < 2; ++r2) {
#pragma unroll
      for (int mi = 0; mi < 7; ++mi)
#pragma unroll
        for (int nh = 0; nh < 2; ++nh) {
          int ni = r2 * 2 + nh;
#pragma unroll
          for (int q = 0; q < 4; ++q) {
            int pl = mi * 16 + l4 * 4 + q;
            unsigned int pk = ypk[mi][ni][q >> 1];
            float yp = __uint_as_float((q & 1) ? (pk & 0xffff0000u) : (pk << 16));
            float yr = acc[mi][ni][q];
            float dg = 1.f / (1.f + __expf(-2.f * (yp - th[ni])));
            float v = (yp + dg * yr) * sc[ni] + bi[ni];
            *(float*)(slice + (nh * 16 + l15) * 464 + pl * 4) = v;
          }
        }
#pragma unroll
      for (int it = 0; it < 16; ++it) {
        int j = it * 64 + lane;              // 64 rows x 16 (14 used) f4-units
        int r = j >> 4, x4 = j & 15;
        if (x4 < 14) {
          int o_loc = r >> 1, yl = r & 1;
          int oc = wn * 64 + r2 * 32 + o_loc;
          int gy = rg * 4 + wm * 2 + yl;
          size_t gb = ((size_t)(img * 256 + oc) * 56 + gy) * 56 + x4 * 4;
          const float4 xa = *(const float4*)(xres + gb);
          const float4 hv = *(const float4*)(slice + o_loc * 464 +
                                             (yl * 56 + x4 * 4) * 4);
          float4 o4;
          o4.x = fmaxf(xa.x + hv.x, 0.f);
          o4.y = fmaxf(xa.y + hv.y, 0.f);
          o4.z = fmaxf(xa.z + hv.z, 0.f);
          o4.w = fmaxf(xa.w + hv.w, 0.f);
          *(float4*)(dout + gb) = o4;
        }
      }
    }
  }
}

// ----------------------------------------------------------------
extern "C" void kernel_launch(void* const* d_in, const int* in_sizes, int n_in,
                              void* d_out, int out_size, void* d_ws, size_t ws_size,
                              hipStream_t stream) {
  const float* x    = (const float*)d_in[0];
  const float* w_a  = (const float*)d_in[1];
  const float* th_a = (const float*)d_in[2];
  const float* ga_a = (const float*)d_in[3];
  const float* be_a = (const float*)d_in[4];
  const float* mu_a = (const float*)d_in[5];
  const float* va_a = (const float*)d_in[6];
  const float* w_b  = (const float*)d_in[7];
  const float* th_b = (const float*)d_in[8];
  const float* ga_b = (const float*)d_in[9];
  const float* be_b = (const float*)d_in[10];
  const float* mu_b = (const float*)d_in[11];
  const float* va_b = (const float*)d_in[12];
  float* out = (float*)d_out;

  char* ws = (char*)d_ws;
  unsigned short* xpad = (unsigned short*)ws;
  unsigned short* hpad = (unsigned short*)(ws + 27558912);
  unsigned short* bta  = (unsigned short*)(ws + 2 * 27558912);
  unsigned short* btb  = (unsigned short*)(ws + 2 * 27558912 + 1179648);
  (void)ws_size; (void)in_sizes; (void)n_in; (void)out_size;

  hipLaunchKernelGGL(zero_borders, dim3(NIMG * HP), dim3(256), 0, stream, hpad);
  hipLaunchKernelGGL(prep_w, dim3(512), dim3(256), 0, stream, w_a, w_b, bta, btb);
  hipLaunchKernelGGL(prep_x, dim3(NIMG * HP), dim3(256), 0, stream, x, xpad);

  hipLaunchKernelGGL((conv_cg<1>), dim3(NIMG * 14), dim3(512), 0, stream,
                     xpad, bta, th_a, ga_a, be_a, mu_a, va_a,
                     hpad, (const float*)nullptr, (float*)nullptr);
  hipLaunchKernelGGL((conv_cg<2>), dim3(NIMG * 14), dim3(512), 0, stream,
                     hpad, btb, th_b, ga_b, be_b, mu_b, va_b,
                     (unsigned short*)nullptr, x, out);
}

// Round 5
// 614.946 us; speedup vs baseline: 1.0048x; 1.0048x over previous
//
#include <hip/hip_runtime.h>
#include <hip/hip_bf16.h>
#include <cstdint>
#include <cstddef>

// ResNet CG-gated basic block, MI355X gfx950.
// conv_cg: block = 4 rows x 56 cols (224 px) x 256 outs, 512 threads (8 waves,
// wave = 112px x 64o, m7n4 of 16x16x32). A patch (6x58x64ch, 43.5KB) dbuf,
// staged once per cb at tap7, reused by all 9 taps. B (32KB per tap-cb) dbuf,
// 4 loads/thread/tap. Counted vmcnt(4/9), never drained mid-loop. yp packed
// bf16 (VGPR) while yr accumulates (AGPR). Grid 224 = 1 block/CU, no tail.

typedef __attribute__((ext_vector_type(8))) short bf16x8;
typedef __attribute__((ext_vector_type(4))) float f32x4;
typedef __attribute__((ext_vector_type(8))) unsigned short u16x8;

#define HP 58
#define WP 58
#define CIN 256
#define NIMG 16

#define A1_OFF 45056
#define B0_OFF 90112
#define B1_OFF 122880

__device__ __forceinline__ unsigned short f2bf(float f) {
  unsigned int u = __float_as_uint(f);
  u += 0x7fffu + ((u >> 16) & 1u);   // RNE
  return (unsigned short)(u >> 16);
}

#define GLOAD16(gp, lp)                                                        \
  __builtin_amdgcn_global_load_lds(                                            \
      (const __attribute__((address_space(1))) void*)(gp),                     \
      (__attribute__((address_space(3))) void*)(lp), 16, 0, 0)

// ---------------------------------------------------------------- weights
// w OIHW f32 -> Bt[tap][cb][256 o][64 c] bf16 (32KB per (tap,cb) chunk)
__global__ void prep_w(const float* __restrict__ wa, const float* __restrict__ wb,
                       unsigned short* __restrict__ bta, unsigned short* __restrict__ btb) {
  int id = blockIdx.x * 256 + threadIdx.x;   // 0 .. 131071
  const float* w = (id < 65536) ? wa : wb;
  unsigned short* bt = (id < 65536) ? bta : btb;
  int oi = id & 65535;
  int o = oi >> 8, i = oi & 255;
  int cb = i >> 6, c = i & 63;
  float v[9];
#pragma unroll
  for (int t = 0; t < 9; ++t) v[t] = w[(size_t)oi * 9 + t];
#pragma unroll
  for (int t = 0; t < 9; ++t)
    bt[((size_t)((t * 4 + cb) * 256 + o)) * 64 + c] = f2bf(v[t]);
}

// ---------------- x: NCHW f32 -> padded NHWC bf16 (+borders); also zero hpad
__global__ void prep_x(const float* __restrict__ x, unsigned short* __restrict__ xpad,
                       unsigned short* __restrict__ hpad) {
  __shared__ float ld[56 * 65];
  int b = blockIdx.x;              // 16*58 padded rows
  int img = b / 58, y = b - img * 58;
  int tid = threadIdx.x;
  unsigned short* row = xpad + ((size_t)(img * HP + y)) * WP * CIN;
  unsigned short* hrow = hpad + ((size_t)(img * HP + y)) * WP * CIN;
  u16x8 z = {0, 0, 0, 0, 0, 0, 0, 0};
  if (y == 0 || y == HP - 1) {
#pragma unroll
    for (int it = 0; it < 8; ++it) {
      int i = it * 256 + tid;
      if (i < WP * CIN / 8) { ((u16x8*)row)[i] = z; ((u16x8*)hrow)[i] = z; }
    }
    return;
  }
  if (tid < 32) { ((u16x8*)row)[tid] = z; ((u16x8*)hrow)[tid] = z; }
  else if (tid < 64) {
    ((u16x8*)row)[(WP - 1) * CIN / 8 + tid - 32] = z;
    ((u16x8*)hrow)[(WP - 1) * CIN / 8 + tid - 32] = z;
  }
  int ys = y - 1;
  for (int cb = 0; cb < 4; ++cb) {
    __syncthreads();
#pragma unroll
    for (int it = 0; it < 14; ++it) {
      int i = tid + it * 256;                      // 64 ch * 56 x
      int cl = i / 56, xx = i - cl * 56;
      ld[xx * 65 + cl] = x[((size_t)(img * 256 + cb * 64 + cl) * 56 + ys) * 56 + xx];
    }
    __syncthreads();
#pragma unroll
    for (int it = 0; it < 14; ++it) {
      int j = tid + it * 256;
      int xx = j >> 6, c = j & 63;
      row[(xx + 1) * CIN + cb * 64 + c] = f2bf(ld[xx * 65 + c]);
    }
  }
}

// ---------------------------------------------------------------- CG conv + BN
template <int LAYER>
__global__ __launch_bounds__(512, 2)
void conv_cg(const unsigned short* __restrict__ inp,   // [16][58][58][256] bf16
             const unsigned short* __restrict__ Bt,    // [9][4][256][64] bf16
             const float* __restrict__ theta,
             const float* __restrict__ gammav,
             const float* __restrict__ betav,
             const float* __restrict__ meanv,
             const float* __restrict__ varv,
             unsigned short* __restrict__ hout,        // LAYER==1
             const float* __restrict__ xres,           // LAYER==2
             float* __restrict__ dout)                 // LAYER==2
{
  __shared__ alignas(16) char smem[155648];  // A0|A1 (45056 ea) B0|B1 (32768 ea)

  const int tid = threadIdx.x;
  const int lane = tid & 63;
  const int wid = tid >> 6;
  const int wm = wid >> 2, wn = wid & 3;     // wave = px-half x o-quarter
  const int l15 = lane & 15, l4 = lane >> 4;

  int bx = blockIdx.x;
  int sw = (bx & 7) * 28 + (bx >> 3);        // XCD-bijective (224 = 8*28)
  const int img = sw / 14, rg = sw - img * 14;   // rows rg*4 .. rg*4+3
  const size_t img_base = (size_t)img * (HP * WP * CIN);
  // patch origin: padded row rg*4, col 0
  const char* inb = (const char*)(inp + img_base) + (size_t)(rg * 4 * WP) * 512;
  const char* Btb = (const char*)Bt;

  // MFMA read precomputes (keep: used 8x/chunk)
  int pb[7];
#pragma unroll
  for (int mi = 0; mi < 7; ++mi) {
    int pl = mi * 16 + l15;                  // wave-local px 0..111
    int ar = pl / 56, ac = pl - ar * 56;
    pb[mi] = (wm * 2 + ar + 1) * 58 + ac + 1;
  }
  int ro128[4], rx7[4];
#pragma unroll
  for (int ni = 0; ni < 4; ++ni) {
    int ro = wn * 64 + ni * 16 + l15;
    ro128[ni] = ro << 7;
    rx7[ni] = ro & 7;
  }

  // staging: offsets recomputed per call (saves VGPRs)
  auto stageA = [&](int abuf, int cb) {     // 6x58 px x 64ch = 2784 16B-units
    const char* s0 = inb + cb * 128;
#pragma unroll
    for (int it = 0; it < 6; ++it) {
      int u = it * 512 + tid;
      if (it < 5 || u < 2784) {
        int p = u >> 3, s = u & 7;
        GLOAD16(s0 + p * 512 + ((s ^ (p & 7)) << 4),
                smem + abuf + it * 8192 + wid * 1024);
      }
    }
  };
  auto stageB = [&](int bbuf, int chunk) {   // chunk = tap*4+cb, 2048 units
    const char* s0 = Btb + (size_t)chunk * 32768;
#pragma unroll
    for (int it = 0; it < 4; ++it) {
      int u = it * 512 + tid;
      int o = u >> 3, s = u & 7;
      GLOAD16(s0 + o * 128 + ((s ^ (o & 7)) << 4),
              smem + bbuf + it * 8192 + wid * 1024);
    }
  };

  f32x4 acc[7][4];
  unsigned int ypk[7][4][2];
  const f32x4 fzero = {0.f, 0.f, 0.f, 0.f};
#pragma unroll
  for (int i = 0; i < 7; ++i)
#pragma unroll
    for (int j = 0; j < 4; ++j) acc[i][j] = fzero;

  stageA(0, 0);          // queue: [A(5|6), B(4)]
  stageB(B0_OFF, 0);

#pragma unroll 1
  for (int cb = 0; cb < 4; ++cb) {
    const char* Abp = smem + ((cb & 1) ? A1_OFF : 0);
    const int An = (cb & 1) ? 0 : A1_OFF;
#pragma unroll
    for (int tap = 0; tap < 9; ++tap) {
      const int dyy = (tap / 3 - 1) * 58 + (tap % 3 - 1);
      const char* Bcp = smem + (((cb + tap) & 1) ? B1_OFF : B0_OFF);
      const int Bn = ((cb + tap) & 1) ? B0_OFF : B1_OFF;
      // issue next-chunk stages (stay in flight across barriers)
      if (tap < 8) stageB(Bn, (tap + 1) * 4 + cb);
      else if (cb < 3) stageB(Bn, cb + 1);       // tap0 of next cb
      if (tap == 7 && cb < 3) stageA(An, cb + 1);
      // counted wait: current B (and, at tap0, current A) resident
      if (cb == 3 && tap == 8)
        asm volatile("s_waitcnt vmcnt(0)" ::: "memory");
      else if (cb < 3 && (tap == 7 || tap == 8))
        asm volatile("s_waitcnt vmcnt(9)" ::: "memory");
      else
        asm volatile("s_waitcnt vmcnt(4)" ::: "memory");
      __builtin_amdgcn_s_barrier();
      __builtin_amdgcn_sched_barrier(0);
      __builtin_amdgcn_s_setprio(1);
#pragma unroll
      for (int ks = 0; ks < 2; ++ks) {
        bf16x8 bv[4];
#pragma unroll
        for (int ni = 0; ni < 4; ++ni)
          bv[ni] = *(const bf16x8*)(Bcp + ro128[ni] +
                                    (((ks * 4 + l4) ^ rx7[ni]) << 4));
#pragma unroll
        for (int mi = 0; mi < 7; ++mi) {
          int p = pb[mi] + dyy;
          bf16x8 av = *(const bf16x8*)(Abp + p * 128 +
                                       (((ks * 4 + l4) ^ (p & 7)) << 4));
#pragma unroll
          for (int ni = 0; ni < 4; ++ni)
            acc[mi][ni] = __builtin_amdgcn_mfma_f32_16x16x32_bf16(
                av, bv[ni], acc[mi][ni], 0, 0, 0);
        }
      }
      __builtin_amdgcn_s_setprio(0);
      __builtin_amdgcn_s_barrier();
    }
    if (cb == 0) {   // yp complete -> pack to bf16 pairs, reset acc
#pragma unroll
      for (int mi = 0; mi < 7; ++mi)
#pragma unroll
        for (int ni = 0; ni < 4; ++ni) {
          ypk[mi][ni][0] = (unsigned int)f2bf(acc[mi][ni][0]) |
                           ((unsigned int)f2bf(acc[mi][ni][1]) << 16);
          ypk[mi][ni][1] = (unsigned int)f2bf(acc[mi][ni][2]) |
                           ((unsigned int)f2bf(acc[mi][ni][3]) << 16);
          acc[mi][ni] = fzero;
        }
    }
  }
  __syncthreads();   // LDS reused as epilogue scratch

  // ---- epilogue: gate + BN (+relu / +residual); per-wave private slice
  char* slice = smem + wid * 19456;
  float th[4], sc[4], bi[4];
#pragma unroll
  for (int ni = 0; ni < 4; ++ni) {
    int o = wn * 64 + ni * 16 + l15;
    th[ni] = theta[o];
    float inv = gammav[o] * rsqrtf(varv[o] + 1e-5f);
    sc[ni] = inv;
    bi[ni] = betav[o] - meanv[o] * inv;
  }

  if (LAYER == 1) {
    // stage wave tile [112 px][64 o] bf16 (row stride 144B), store NHWC
#pragma unroll
    for (int mi = 0; mi < 7; ++mi)
#pragma unroll
      for (int ni = 0; ni < 4; ++ni)
#pragma unroll
        for (int q = 0; q < 4; ++q) {
          int pl = mi * 16 + l4 * 4 + q;
          unsigned int pk = ypk[mi][ni][q >> 1];
          float yp = __uint_as_float((q & 1) ? (pk & 0xffff0000u) : (pk << 16));
          float yr = acc[mi][ni][q];
          float dg = 1.f / (1.f + __expf(-2.f * (yp - th[ni])));
          float v = fmaxf((yp + dg * yr) * sc[ni] + bi[ni], 0.f);
          *(unsigned short*)(slice + pl * 144 + (ni * 16 + l15) * 2) = f2bf(v);
        }
#pragma unroll
    for (int it = 0; it < 14; ++it) {
      int j = it * 64 + lane;                // 112 px * 8 octets
      int pl = j >> 3, s = j & 7;
      int lr = pl / 56, xc = pl - lr * 56;
      int gy = rg * 4 + wm * 2 + lr + 1, gx = xc + 1;
      u16x8 tv = *(const u16x8*)(slice + pl * 144 + s * 16);
      *(u16x8*)(hout + img_base + ((size_t)(gy * WP + gx)) * CIN +
                wn * 64 + s * 8) = tv;
    }
  } else {
    // two o-halves of 32: stage [32 o][112 px] f32 (row stride 464B)
#pragma unroll
    for (int r2 = 0; r2 < 2; ++r2) {
#pragma unroll
      for (int mi = 0; mi < 7; ++mi)
#pragma unroll
        for (int nh = 0; nh < 2; ++nh) {
          int ni = r2 * 2 + nh;
#pragma unroll
          for (int q = 0; q < 4; ++q) {
            int pl = mi * 16 + l4 * 4 + q;
            unsigned int pk = ypk[mi][ni][q >> 1];
            float yp = __uint_as_float((q & 1) ? (pk & 0xffff0000u) : (pk << 16));
            float yr = acc[mi][ni][q];
            float dg = 1.f / (1.f + __expf(-2.f * (yp - th[ni])));
            float v = (yp + dg * yr) * sc[ni] + bi[ni];
            *(float*)(slice + (nh * 16 + l15) * 464 + pl * 4) = v;
          }
        }
#pragma unroll
      for (int it = 0; it < 16; ++it) {
        int j = it * 64 + lane;              // 64 rows x 16 (14 used) f4-units
        int r = j >> 4, x4 = j & 15;
        if (x4 < 14) {
          int o_loc = r >> 1, yl = r & 1;
          int oc = wn * 64 + r2 * 32 + o_loc;
          int gy = rg * 4 + wm * 2 + yl;
          size_t gb = ((size_t)(img * 256 + oc) * 56 + gy) * 56 + x4 * 4;
          const float4 xa = *(const float4*)(xres + gb);
          const float4 hv = *(const float4*)(slice + o_loc * 464 +
                                             (yl * 56 + x4 * 4) * 4);
          float4 o4;
          o4.x = fmaxf(xa.x + hv.x, 0.f);
          o4.y = fmaxf(xa.y + hv.y, 0.f);
          o4.z = fmaxf(xa.z + hv.z, 0.f);
          o4.w = fmaxf(xa.w + hv.w, 0.f);
          *(float4*)(dout + gb) = o4;
        }
      }
    }
  }
}

// ----------------------------------------------------------------
extern "C" void kernel_launch(void* const* d_in, const int* in_sizes, int n_in,
                              void* d_out, int out_size, void* d_ws, size_t ws_size,
                              hipStream_t stream) {
  const float* x    = (const float*)d_in[0];
  const float* w_a  = (const float*)d_in[1];
  const float* th_a = (const float*)d_in[2];
  const float* ga_a = (const float*)d_in[3];
  const float* be_a = (const float*)d_in[4];
  const float* mu_a = (const float*)d_in[5];
  const float* va_a = (const float*)d_in[6];
  const float* w_b  = (const float*)d_in[7];
  const float* th_b = (const float*)d_in[8];
  const float* ga_b = (const float*)d_in[9];
  const float* be_b = (const float*)d_in[10];
  const float* mu_b = (const float*)d_in[11];
  const float* va_b = (const float*)d_in[12];
  float* out = (float*)d_out;

  char* ws = (char*)d_ws;
  unsigned short* xpad = (unsigned short*)ws;
  unsigned short* hpad = (unsigned short*)(ws + 27558912);
  unsigned short* bta  = (unsigned short*)(ws + 2 * 27558912);
  unsigned short* btb  = (unsigned short*)(ws + 2 * 27558912 + 1179648);
  (void)ws_size; (void)in_sizes; (void)n_in; (void)out_size;

  hipLaunchKernelGGL(prep_w, dim3(512), dim3(256), 0, stream, w_a, w_b, bta, btb);
  hipLaunchKernelGGL(prep_x, dim3(NIMG * HP), dim3(256), 0, stream, x, xpad, hpad);

  hipLaunchKernelGGL((conv_cg<1>), dim3(NIMG * 14), dim3(512), 0, stream,
                     xpad, bta, th_a, ga_a, be_a, mu_a, va_a,
                     hpad, (const float*)nullptr, (float*)nullptr);
  hipLaunchKernelGGL((conv_cg<2>), dim3(NIMG * 14), dim3(512), 0, stream,
                     hpad, btb, th_b, ga_b, be_b, mu_b, va_b,
                     (unsigned short*)nullptr, x, out);
}